// Round 8
// baseline (78.070 us; speedup 1.0000x reference)
//
#include <hip/hip_runtime.h>
#include <math.h>

// ---------------------------------------------------------------------------
// ScatteringNetwork:
//   img [8,1,256,256] f32, psi_re/psi_im [10,1,11,11] f32, blur_k [7,7] f32
//   out: concat([s0(1ch), s1_out(10ch), s2_out(100ch)]) at 32x32 -> [8, 111*1024]
//
// blur(conv(x,psi))[::8] == conv(x, psi (*) blur)[::8]. blur = g (x) g and
// psi_k = F_k (x) H_k (both rank-1 exact) -> composed 17x17 kernel is rank-2:
// comb_k = F'r(x)H'r - F'i(x)H'i, F' = a (*) F, H' = b (*) H. Blur-pad clip at
// Y==0 / X==0 only clips a / b -> variant factors F'' / H'' (rare paths).
//
// R8: sources stored PADDED (272x272, zero borders) in ws -> k_main4 row pass
// reads unpredicated float4 from L1/L2-hot global; LDS = inter only (36 KB,
// 4 blocks/CU); one barrier per block; F' preloaded before row pass.
//
// ws layout (floats):
//   [0)        pimg   : 8  * 272*272 = 591,872   (img padded, zero border 8)
//   [591872)   s1p    : 80 * 272*272 = 5,918,720 (s1abs padded)
//   [6510592)  fhp    : 10*136
// fhp per ch: [0)H'r [17)H'i [34)H''r [51)H''i [68)F'r [85)F'i [102)F''r [119)F''i
// ---------------------------------------------------------------------------

#define PIMG_SZ  73984          // 272*272
#define PIMG_OFF 0
#define S1P_OFF  591872
#define FHP_OFF  6510592

// ---------------- k_s1: separable Morlet |conv|, wave-per-channel ----------
__global__ __launch_bounds__(640) void k_s1(const float* __restrict__ img,
                                            const float* __restrict__ psi_re,
                                            const float* __restrict__ psi_im,
                                            const float* __restrict__ blur,
                                            float* __restrict__ pimg,
                                            float* __restrict__ s1p,
                                            float* __restrict__ fhp) {
    if (blockIdx.z == 8) {        // setup slice: fhp + padded copies / borders
        int bid = blockIdx.y * 16 + blockIdx.x;       // 0..255
        int g = bid * 640 + threadIdx.x;              // 0..163839
        if (g < 1360) {
            int ch = g / 136;
            int w = g - ch * 136;
            int part = w / 17;
            int i = w - part * 17;
            const float* pr = psi_re + ch * 121;
            const float* pi = psi_im + ch * 121;
            float val = 0.f;
            if (part < 4) {                       // H-type: H_j = psi[5][j]
                int qmin = (part >= 2) ? 3 : 0;
                int comp = part & 1;
                float bden = blur[24];
                for (int q = qmin; q < 7; ++q) {
                    int jj = i - q;
                    if (jj < 0 || jj > 10) continue;
                    float bq = blur[21 + q] / bden;
                    float h = comp ? pi[55 + jj] : pr[55 + jj];
                    val += bq * h;
                }
            } else {                              // F-type: F_i = psi[i][5]/psi[5][5]
                int pmin = (part >= 6) ? 3 : 0;
                int comp = part & 1;
                float dr = pr[60], di = pi[60];
                float inv = 1.f / (dr * dr + di * di);
                for (int p = pmin; p < 7; ++p) {
                    int ii = i - p;
                    if (ii < 0 || ii > 10) continue;
                    float ap = blur[p * 7 + 3];
                    float nr = pr[ii * 11 + 5], ni = pi[ii * 11 + 5];
                    float f = comp ? (ni * dr - nr * di) * inv
                                   : (nr * dr + ni * di) * inv;
                    val += ap * f;
                }
            }
            fhp[g] = val;
        }
        // pimg = padded img copy; s1p borders = 0 (interior written by z<8)
        for (long idx = g; idx < 88L * PIMG_SZ; idx += 163840L) {
            int k = (int)(idx / PIMG_SZ);
            int cell = (int)(idx - (long)k * PIMG_SZ);
            int prow = cell / 272, pcol = cell - prow * 272;
            bool inner = (prow >= 8 && prow < 264 && pcol >= 8 && pcol < 264);
            if (k < 8)
                pimg[idx] = inner ? img[k * 65536 + (prow - 8) * 256 + (pcol - 8)] : 0.f;
            else if (!inner)
                s1p[idx - 8L * PIMG_SZ] = 0.f;
        }
        return;
    }

    __shared__ float timg[26 * 27];
    __shared__ float inter[10][26 * 34];
    int tid = threadIdx.x;
    int lane = tid & 63;
    int c = __builtin_amdgcn_readfirstlane(tid >> 6);   // wave = channel 0..9

    const float* pr = psi_re + c * 121;
    const float* pi = psi_im + c * 121;
    float hr[11], hi[11], fr[11], fi[11];
#pragma unroll
    for (int j = 0; j < 11; ++j) { hr[j] = pr[55 + j]; hi[j] = pi[55 + j]; }
#pragma unroll
    for (int i = 0; i < 11; ++i) { fr[i] = pr[i * 11 + 5]; fi[i] = pi[i * 11 + 5]; }
    float dr = pr[60], di = pi[60];
    float inv = rsqrtf(dr * dr + di * di);

    int n = blockIdx.z;
    int y0 = blockIdx.y * 16, x0 = blockIdx.x * 16;
    const float* im = img + n * 65536;
    for (int idx = tid; idx < 676; idx += 640) {
        int r = idx / 26, cc = idx - r * 26;
        int gy = y0 + r - 5, gx = x0 + cc - 5;
        timg[r * 27 + cc] = (gy >= 0 && gy < 256 && gx >= 0 && gx < 256) ? im[gy * 256 + gx] : 0.f;
    }
    __syncthreads();

    int rr = lane >> 1;
    int half = lane & 1;
    if (rr < 26) {
        int cx0 = half * 8;
        float xv[18];
#pragma unroll
        for (int t = 0; t < 18; ++t) xv[t] = timg[rr * 27 + cx0 + t];
#pragma unroll
        for (int m = 0; m < 8; ++m) {
            float ar = 0.f, ai = 0.f;
#pragma unroll
            for (int j = 0; j < 11; ++j) {
                ar = fmaf(hr[j], xv[m + j], ar);
                ai = fmaf(hi[j], xv[m + j], ai);
            }
            inter[c][rr * 34 + 2 * (cx0 + m)]     = ar;
            inter[c][rr * 34 + 2 * (cx0 + m) + 1] = ai;
        }
    }
    __syncthreads();

    int x = lane & 15, yq = lane >> 4;
    int yb = 4 * yq;
    const float* sc = &inter[c][yb * 34 + 2 * x];
    float accr[4] = {0.f, 0.f, 0.f, 0.f};
    float acci[4] = {0.f, 0.f, 0.f, 0.f};
#pragma unroll
    for (int r = 0; r < 14; ++r) {
        float vr = sc[r * 34], vi = sc[r * 34 + 1];
#pragma unroll
        for (int dy = 0; dy < 4; ++dy) {
            if (r - dy >= 0 && r - dy <= 10) {
                float wr = fr[r - dy], wi = fi[r - dy];
                accr[dy] = fmaf(wr, vr, fmaf(-wi, vi, accr[dy]));
                acci[dy] = fmaf(wr, vi, fmaf(wi, vr, acci[dy]));
            }
        }
    }
    float* so = s1p + (size_t)(n * 10 + c) * PIMG_SZ + (8 + y0 + yb) * 272 + (8 + x0 + x);
#pragma unroll
    for (int dy = 0; dy < 4; ++dy)
        so[dy * 272] = inv * sqrtf(accr[dy] * accr[dy] + acci[dy] * acci[dy]);
}

// ---------------- k_main4: rank-2 separable composed conv, no input tile ---
// grid (32 = 16 Ybands x 2 Xhalves, 11 src, 8 n), 320 thr = 5 waves x 2 ch.
__global__ __launch_bounds__(320, 4) void k_main4(const float* __restrict__ pimg,
                                                  const float* __restrict__ s1p,
                                                  const float* __restrict__ fhp,
                                                  const float* __restrict__ blur,
                                                  float* __restrict__ out) {
    __shared__ __align__(16) float inter[10][900];   // 36 KB -> 4 blocks/CU
    int tid = threadIdx.x;
    int bx = blockIdx.x;
    int b = bx >> 1, h = bx & 1;   // Y in {2b,2b+1}, X in [16h,16h+16)
    int src = blockIdx.y;          // 0..10
    int n = blockIdx.z;

    const float* sp = (src == 0) ? pimg + n * PIMG_SZ
                                 : s1p + (size_t)(n * 10 + src - 1) * PIMG_SZ;

    int wave = __builtin_amdgcn_readfirstlane(tid >> 6);
    int lane = tid & 63;
    int chA = wave, chB = wave + 5;
    const float* fA = fhp + chA * 136;   // uniform -> s_load (SGPR weights)
    const float* fB = fhp + chB * 136;
    float HrA[9], HiA[9], HrB[9], HiB[9];
#pragma unroll
    for (int j = 0; j < 9; ++j) {
        HrA[j] = fA[j]; HiA[j] = fA[17 + j];
        HrB[j] = fB[j]; HiB[j] = fB[17 + j];
    }
    // col-pass F' preload (per-lane, issued early to overlap row pass)
    int q = lane >> 5;
    int ysub = (lane >> 4) & 1;
    int Xc = lane & 15;
    const float* fq = q ? fB : fA;
    float Fr[9], Fi[9];
#pragma unroll
    for (int i = 0; i < 9; ++i) { Fr[i] = fq[68 + i]; Fi[i] = fq[85 + i]; }

    float* iA = &inter[wave * 2][0];
    float* iB = &inter[wave * 2 + 1][0];

    // row pass: tasks (rr 0..24, xr 0..3); 4 consecutive lanes share a row
#pragma unroll
    for (int it = 0; it < 2; ++it) {
        int t = lane + 64 * it;
        if (t < 100) {
            int rr = t >> 2, xr = t & 3;
            const float* trow = sp + (16 * b + rr) * 272 + 128 * h + 32 * xr;
            float aR[4] = {0.f,0.f,0.f,0.f}, aI[4] = {0.f,0.f,0.f,0.f};
            float bR[4] = {0.f,0.f,0.f,0.f}, bI[4] = {0.f,0.f,0.f,0.f};
#pragma unroll
            for (int mc = 0; mc < 11; ++mc) {
                float4 xv = *(const float4*)(trow + 4 * mc);
#pragma unroll
                for (int e = 0; e < 4; ++e) {
                    int cidx = 4 * mc + e;
                    float x = (&xv.x)[e];
#pragma unroll
                    for (int w = 0; w < 4; ++w) {
                        int j = cidx - 8 * w;
                        if (j >= 0 && j <= 16) {           // static after unroll
                            int jm = (j < 9) ? j : 16 - j;
                            aR[w] = fmaf(HrA[jm], x, aR[w]);
                            aI[w] = fmaf((j < 9) ? HiA[jm] : -HiA[jm], x, aI[w]);
                            bR[w] = fmaf(HrB[jm], x, bR[w]);
                            bI[w] = fmaf((j < 9) ? HiB[jm] : -HiB[jm], x, bI[w]);
                        }
                    }
                }
            }
            float* dA = iA + rr * 36 + 8 * xr;
            float* dB = iB + rr * 36 + 8 * xr;
            float4 a0 = {aR[0], aI[0], aR[1], aI[1]};
            float4 a1 = {aR[2], aI[2], aR[3], aI[3]};
            float4 b0 = {bR[0], bI[0], bR[1], bI[1]};
            float4 b1 = {bR[2], bI[2], bR[3], bI[3]};
            *(float4*)dA = a0; *(float4*)(dA + 4) = a1;
            *(float4*)dB = b0; *(float4*)(dB + 4) = b1;
        }
    }

    // X global == 0 slot redo with clipped H'' (h==0 blocks; weights uniform)
    if (h == 0 && lane < 25) {
        int rr = lane;
        const float* trow0 = sp + (16 * b + rr) * 272;   // padded cols 0..16
        float sRA = 0.f, sIA = 0.f, sRB = 0.f, sIB = 0.f;
#pragma unroll
        for (int j = 0; j < 17; ++j) {
            float x = trow0[j];
            sRA = fmaf(fA[34 + j], x, sRA);
            sIA = fmaf(fA[51 + j], x, sIA);
            sRB = fmaf(fB[34 + j], x, sRB);
            sIB = fmaf(fB[51 + j], x, sIB);
        }
        iA[rr * 36] = sRA; iA[rr * 36 + 1] = sIA;
        iB[rr * 36] = sRB; iB[rr * 36 + 1] = sIB;
    }
    __syncthreads();

    // col pass: lane = (q:2, ysub:2, Xc:16) -> one output each
    int Y = 2 * b + ysub;
    const float* isl = q ? iB : iA;
    float acc = 0.f;
#pragma unroll
    for (int i = 0; i < 17; ++i) {
        float vr = isl[(8 * ysub + i) * 36 + 2 * Xc];
        float vi = isl[(8 * ysub + i) * 36 + 2 * Xc + 1];
        int im_ = (i < 9) ? i : 16 - i;
        float fr_ = Fr[im_];
        float fi_ = (i < 9) ? Fi[im_] : -Fi[im_];
        acc = fmaf(fr_, vr, acc);
        acc = fmaf(-fi_, vi, acc);
    }
    if (Y == 0) {                 // b==0 blocks (1/16): clipped F'' recompute
        acc = 0.f;
#pragma unroll
        for (int i = 0; i < 17; ++i) {
            float vr = isl[i * 36 + 2 * Xc];
            float vi = isl[i * 36 + 2 * Xc + 1];
            acc = fmaf(fq[102 + i], vr, acc);
            acc = fmaf(-fq[119 + i], vi, acc);
        }
    }
    int ch = q ? chB : chA;
    int ch_out = (src == 0) ? 1 + ch : 11 + (src - 1) * 10 + ch;
    size_t nb = (size_t)n * 111 * 1024;
    out[nb + (size_t)ch_out * 1024 + Y * 32 + 16 * h + Xc] = acc;

    // s0: exact clipped 7x7 blur at stride 8, from padded img
    if (src == 0 && wave == 0 && lane < 32) {
        int ys = lane >> 4, Xs = lane & 15;
        const float* pim = pimg + n * PIMG_SZ;
        float s0 = 0.f;
#pragma unroll
        for (int p = 0; p < 7; ++p)
#pragma unroll
            for (int qq = 0; qq < 7; ++qq)
                s0 = fmaf(blur[p * 7 + qq],
                          pim[(16 * b + 8 * ys + p + 5) * 272 + 128 * h + 8 * Xs + qq + 5], s0);
        out[nb + (2 * b + ys) * 32 + 16 * h + Xs] = s0;
    }
}

extern "C" void kernel_launch(void* const* d_in, const int* in_sizes, int n_in,
                              void* d_out, int out_size, void* d_ws, size_t ws_size,
                              hipStream_t stream) {
    const float* img    = (const float*)d_in[0];
    const float* psi_re = (const float*)d_in[1];
    const float* psi_im = (const float*)d_in[2];
    const float* blur   = (const float*)d_in[3];
    float* out = (float*)d_out;
    float* ws = (float*)d_ws;
    float* pimg = ws + PIMG_OFF;
    float* s1p  = ws + S1P_OFF;
    float* fhp  = ws + FHP_OFF;

    dim3 g1(16, 16, 9);
    k_s1<<<g1, 640, 0, stream>>>(img, psi_re, psi_im, blur, pimg, s1p, fhp);

    dim3 g2(32, 11, 8);
    k_main4<<<g2, 320, 0, stream>>>(pimg, s1p, fhp, blur, out);
}

// Round 9
// 69.122 us; speedup vs baseline: 1.1295x; 1.1295x over previous
//
#include <hip/hip_runtime.h>
#include <math.h>

// ---------------------------------------------------------------------------
// ScatteringNetwork:
//   img [8,1,256,256] f32, psi_re/psi_im [10,1,11,11] f32, blur_k [7,7] f32
//   out: concat([s0(1ch), s1_out(10ch), s2_out(100ch)]) at 32x32 -> [8, 111*1024]
//
// blur(conv(x,psi))[::8] == conv(x, psi (*) blur)[::8]. blur = g (x) g and
// psi_k = F_k (x) H_k (both rank-1 exact) -> composed 17x17 kernel is rank-2:
// comb_k = F'r(x)H'r - F'i(x)H'i, F' = a (*) F, H' = b (*) H. Blur-pad clip at
// Y==0 / X==0 only clips a / b -> variant factors F'' / H'' (rare paths).
//
// R9: (1) setup slice uses cheap 32-bit addressing (R8's 64-bit div loop was
// ~27us); (2) k_main5 preloads the 11 row float4s into a register array so
// the L2 loads batch-issue (R8's VGPR=48 serialized them, ~4400 stall
// cyc/task -> VALUBusy 17.8%).
//
// ws layout (floats):
//   [0)        pimg   : 8  * 272*272 = 591,872   (img padded, zero border 8)
//   [591872)   s1p    : 80 * 272*272 = 5,918,720 (s1abs padded)
//   [6510592)  fhp    : 10*136
// fhp per ch: [0)H'r [17)H'i [34)H''r [51)H''i [68)F'r [85)F'i [102)F''r [119)F''i
// ---------------------------------------------------------------------------

#define PIMG_SZ  73984          // 272*272
#define PIMG_OFF 0
#define S1P_OFF  591872
#define FHP_OFF  6510592

// ---------------- k_s1: separable Morlet |conv|, wave-per-channel ----------
__global__ __launch_bounds__(640) void k_s1(const float* __restrict__ img,
                                            const float* __restrict__ psi_re,
                                            const float* __restrict__ psi_im,
                                            const float* __restrict__ blur,
                                            float* __restrict__ pimg,
                                            float* __restrict__ s1p,
                                            float* __restrict__ fhp) {
    if (blockIdx.z == 8) {        // setup slice: fhp + pimg copy + s1p borders
        int bid = blockIdx.y * 16 + blockIdx.x;       // 0..255
        int tid = threadIdx.x;
        if (bid == 0) {
            for (int g = tid; g < 1360; g += 640) {
                int ch = g / 136;
                int w = g - ch * 136;
                int part = w / 17;
                int i = w - part * 17;
                const float* pr = psi_re + ch * 121;
                const float* pi = psi_im + ch * 121;
                float val = 0.f;
                if (part < 4) {                       // H-type: H_j = psi[5][j]
                    int qmin = (part >= 2) ? 3 : 0;
                    int comp = part & 1;
                    float bden = blur[24];
                    for (int q = qmin; q < 7; ++q) {
                        int jj = i - q;
                        if (jj < 0 || jj > 10) continue;
                        float bq = blur[21 + q] / bden;
                        float hh = comp ? pi[55 + jj] : pr[55 + jj];
                        val += bq * hh;
                    }
                } else {                              // F-type: F_i = psi[i][5]/psi[5][5]
                    int pmin = (part >= 6) ? 3 : 0;
                    int comp = part & 1;
                    float dr = pr[60], di = pi[60];
                    float inv = 1.f / (dr * dr + di * di);
                    for (int p = pmin; p < 7; ++p) {
                        int ii = i - p;
                        if (ii < 0 || ii > 10) continue;
                        float ap = blur[p * 7 + 3];
                        float nr = pr[ii * 11 + 5], ni = pi[ii * 11 + 5];
                        float f = comp ? (ni * dr - nr * di) * inv
                                       : (nr * dr + ni * di) * inv;
                        val += ap * f;
                    }
                }
                fhp[g] = val;
            }
        } else if (bid <= 32) {
            // pimg copy (float4): image n, row-quarter q of the 272 padded rows
            int n = (bid - 1) >> 2;
            int q = (bid - 1) & 3;
            float* dst = pimg + n * PIMG_SZ;
            const float* src = img + n * 65536;
            for (int idx = tid; idx < 68 * 68; idx += 640) {
                int pr = 68 * q + idx / 68;
                int c4 = idx - (idx / 68) * 68;
                float4 v = {0.f, 0.f, 0.f, 0.f};
                if (pr >= 8 && pr < 264 && c4 >= 2 && c4 < 66)
                    v = *(const float4*)(src + (pr - 8) * 256 + (4 * c4 - 8));
                *(float4*)(dst + pr * 272 + 4 * c4) = v;
            }
        } else if (bid <= 72) {
            // s1p border zero: 2 channel-images per block, 8448 border cells each
            int u = (bid - 33) * 2;
            for (int k = u; k < u + 2; ++k) {
                float* base = s1p + (size_t)k * PIMG_SZ;
                for (int e = tid; e < 8448; e += 640) {
                    int row, col;
                    if (e < 2176) {            // top 8 rows
                        row = e / 272; col = e - row * 272;
                    } else if (e < 4352) {     // bottom 8 rows
                        int e2 = e - 2176;
                        int r2 = e2 / 272;
                        row = 264 + r2; col = e2 - r2 * 272;
                    } else {                   // left/right 8-col strips
                        int e2 = e - 4352;
                        row = 8 + (e2 >> 4);
                        int cc = e2 & 15;
                        col = (cc < 8) ? cc : 256 + cc;
                    }
                    base[row * 272 + col] = 0.f;
                }
            }
        }
        return;
    }

    __shared__ float timg[26 * 27];
    __shared__ float inter[10][26 * 34];
    int tid = threadIdx.x;
    int lane = tid & 63;
    int c = __builtin_amdgcn_readfirstlane(tid >> 6);   // wave = channel 0..9

    const float* pr = psi_re + c * 121;
    const float* pi = psi_im + c * 121;
    float hr[11], hi[11], fr[11], fi[11];
#pragma unroll
    for (int j = 0; j < 11; ++j) { hr[j] = pr[55 + j]; hi[j] = pi[55 + j]; }
#pragma unroll
    for (int i = 0; i < 11; ++i) { fr[i] = pr[i * 11 + 5]; fi[i] = pi[i * 11 + 5]; }
    float dr = pr[60], di = pi[60];
    float inv = rsqrtf(dr * dr + di * di);

    int n = blockIdx.z;
    int y0 = blockIdx.y * 16, x0 = blockIdx.x * 16;
    const float* im = img + n * 65536;
    for (int idx = tid; idx < 676; idx += 640) {
        int r = idx / 26, cc = idx - r * 26;
        int gy = y0 + r - 5, gx = x0 + cc - 5;
        timg[r * 27 + cc] = (gy >= 0 && gy < 256 && gx >= 0 && gx < 256) ? im[gy * 256 + gx] : 0.f;
    }
    __syncthreads();

    int rr = lane >> 1;
    int half = lane & 1;
    if (rr < 26) {
        int cx0 = half * 8;
        float xv[18];
#pragma unroll
        for (int t = 0; t < 18; ++t) xv[t] = timg[rr * 27 + cx0 + t];
#pragma unroll
        for (int m = 0; m < 8; ++m) {
            float ar = 0.f, ai = 0.f;
#pragma unroll
            for (int j = 0; j < 11; ++j) {
                ar = fmaf(hr[j], xv[m + j], ar);
                ai = fmaf(hi[j], xv[m + j], ai);
            }
            inter[c][rr * 34 + 2 * (cx0 + m)]     = ar;
            inter[c][rr * 34 + 2 * (cx0 + m) + 1] = ai;
        }
    }
    __syncthreads();

    int x = lane & 15, yq = lane >> 4;
    int yb = 4 * yq;
    const float* sc = &inter[c][yb * 34 + 2 * x];
    float accr[4] = {0.f, 0.f, 0.f, 0.f};
    float acci[4] = {0.f, 0.f, 0.f, 0.f};
#pragma unroll
    for (int r = 0; r < 14; ++r) {
        float vr = sc[r * 34], vi = sc[r * 34 + 1];
#pragma unroll
        for (int dy = 0; dy < 4; ++dy) {
            if (r - dy >= 0 && r - dy <= 10) {
                float wr = fr[r - dy], wi = fi[r - dy];
                accr[dy] = fmaf(wr, vr, fmaf(-wi, vi, accr[dy]));
                acci[dy] = fmaf(wr, vi, fmaf(wi, vr, acci[dy]));
            }
        }
    }
    float* so = s1p + (size_t)(n * 10 + c) * PIMG_SZ + (8 + y0 + yb) * 272 + (8 + x0 + x);
#pragma unroll
    for (int dy = 0; dy < 4; ++dy)
        so[dy * 272] = inv * sqrtf(accr[dy] * accr[dy] + acci[dy] * acci[dy]);
}

// ---------------- k_main5: rank-2 separable composed conv, no input tile ---
// grid (32 = 16 Ybands x 2 Xhalves, 11 src, 8 n), 320 thr = 5 waves x 2 ch.
__global__ __launch_bounds__(320, 4) void k_main5(const float* __restrict__ pimg,
                                                  const float* __restrict__ s1p,
                                                  const float* __restrict__ fhp,
                                                  const float* __restrict__ blur,
                                                  float* __restrict__ out) {
    __shared__ __align__(16) float inter[10][900];   // 36 KB -> 4 blocks/CU
    int tid = threadIdx.x;
    int bx = blockIdx.x;
    int b = bx >> 1, h = bx & 1;   // Y in {2b,2b+1}, X in [16h,16h+16)
    int src = blockIdx.y;          // 0..10
    int n = blockIdx.z;

    const float* sp = (src == 0) ? pimg + n * PIMG_SZ
                                 : s1p + (size_t)(n * 10 + src - 1) * PIMG_SZ;

    int wave = __builtin_amdgcn_readfirstlane(tid >> 6);
    int lane = tid & 63;
    int chA = wave, chB = wave + 5;
    const float* fA = fhp + chA * 136;   // uniform -> s_load (SGPR weights)
    const float* fB = fhp + chB * 136;
    float HrA[9], HiA[9], HrB[9], HiB[9];
#pragma unroll
    for (int j = 0; j < 9; ++j) {
        HrA[j] = fA[j]; HiA[j] = fA[17 + j];
        HrB[j] = fB[j]; HiB[j] = fB[17 + j];
    }
    // col-pass F' preload (per-lane, issued early to overlap row pass)
    int q = lane >> 5;
    int ysub = (lane >> 4) & 1;
    int Xc = lane & 15;
    const float* fq = q ? fB : fA;
    float Fr[9], Fi[9];
#pragma unroll
    for (int i = 0; i < 9; ++i) { Fr[i] = fq[68 + i]; Fi[i] = fq[85 + i]; }

    float* iA = &inter[wave * 2][0];
    float* iB = &inter[wave * 2 + 1][0];

    // row pass: tasks (rr 0..24, xr 0..3); 4 consecutive lanes share a row.
    // 11 float4 preloaded into regs -> loads batch-issue (the R8 fix).
#pragma unroll
    for (int it = 0; it < 2; ++it) {
        int t = lane + 64 * it;
        if (t < 100) {
            int rr = t >> 2, xr = t & 3;
            const float* trow = sp + (16 * b + rr) * 272 + 128 * h + 32 * xr;
            float4 xv[11];
#pragma unroll
            for (int mc = 0; mc < 11; ++mc)
                xv[mc] = *(const float4*)(trow + 4 * mc);
            float aR[4] = {0.f,0.f,0.f,0.f}, aI[4] = {0.f,0.f,0.f,0.f};
            float bR[4] = {0.f,0.f,0.f,0.f}, bI[4] = {0.f,0.f,0.f,0.f};
#pragma unroll
            for (int mc = 0; mc < 11; ++mc) {
#pragma unroll
                for (int e = 0; e < 4; ++e) {
                    int cidx = 4 * mc + e;
                    float x = (&xv[mc].x)[e];
#pragma unroll
                    for (int w = 0; w < 4; ++w) {
                        int j = cidx - 8 * w;
                        if (j >= 0 && j <= 16) {           // static after unroll
                            int jm = (j < 9) ? j : 16 - j;
                            aR[w] = fmaf(HrA[jm], x, aR[w]);
                            aI[w] = fmaf((j < 9) ? HiA[jm] : -HiA[jm], x, aI[w]);
                            bR[w] = fmaf(HrB[jm], x, bR[w]);
                            bI[w] = fmaf((j < 9) ? HiB[jm] : -HiB[jm], x, bI[w]);
                        }
                    }
                }
            }
            float* dA = iA + rr * 36 + 8 * xr;
            float* dB = iB + rr * 36 + 8 * xr;
            float4 a0 = {aR[0], aI[0], aR[1], aI[1]};
            float4 a1 = {aR[2], aI[2], aR[3], aI[3]};
            float4 b0 = {bR[0], bI[0], bR[1], bI[1]};
            float4 b1 = {bR[2], bI[2], bR[3], bI[3]};
            *(float4*)dA = a0; *(float4*)(dA + 4) = a1;
            *(float4*)dB = b0; *(float4*)(dB + 4) = b1;
        }
    }

    // X global == 0 slot redo with clipped H'' (h==0 blocks; weights uniform)
    if (h == 0 && lane < 25) {
        int rr = lane;
        const float* trow0 = sp + (16 * b + rr) * 272;   // padded cols 0..16
        float sRA = 0.f, sIA = 0.f, sRB = 0.f, sIB = 0.f;
#pragma unroll
        for (int j = 0; j < 17; ++j) {
            float x = trow0[j];
            sRA = fmaf(fA[34 + j], x, sRA);
            sIA = fmaf(fA[51 + j], x, sIA);
            sRB = fmaf(fB[34 + j], x, sRB);
            sIB = fmaf(fB[51 + j], x, sIB);
        }
        iA[rr * 36] = sRA; iA[rr * 36 + 1] = sIA;
        iB[rr * 36] = sRB; iB[rr * 36 + 1] = sIB;
    }
    __syncthreads();

    // col pass: lane = (q:2, ysub:2, Xc:16) -> one output each
    int Y = 2 * b + ysub;
    const float* isl = q ? iB : iA;
    float acc = 0.f;
#pragma unroll
    for (int i = 0; i < 17; ++i) {
        float vr = isl[(8 * ysub + i) * 36 + 2 * Xc];
        float vi = isl[(8 * ysub + i) * 36 + 2 * Xc + 1];
        int im_ = (i < 9) ? i : 16 - i;
        float fr_ = Fr[im_];
        float fi_ = (i < 9) ? Fi[im_] : -Fi[im_];
        acc = fmaf(fr_, vr, acc);
        acc = fmaf(-fi_, vi, acc);
    }
    if (Y == 0) {                 // b==0 blocks (1/16): clipped F'' recompute
        acc = 0.f;
#pragma unroll
        for (int i = 0; i < 17; ++i) {
            float vr = isl[i * 36 + 2 * Xc];
            float vi = isl[i * 36 + 2 * Xc + 1];
            acc = fmaf(fq[102 + i], vr, acc);
            acc = fmaf(-fq[119 + i], vi, acc);
        }
    }
    int ch = q ? chB : chA;
    int ch_out = (src == 0) ? 1 + ch : 11 + (src - 1) * 10 + ch;
    size_t nb = (size_t)n * 111 * 1024;
    out[nb + (size_t)ch_out * 1024 + Y * 32 + 16 * h + Xc] = acc;

    // s0: exact clipped 7x7 blur at stride 8, from padded img
    if (src == 0 && wave == 0 && lane < 32) {
        int ys = lane >> 4, Xs = lane & 15;
        const float* pim = pimg + n * PIMG_SZ;
        float s0 = 0.f;
#pragma unroll
        for (int p = 0; p < 7; ++p)
#pragma unroll
            for (int qq = 0; qq < 7; ++qq)
                s0 = fmaf(blur[p * 7 + qq],
                          pim[(16 * b + 8 * ys + p + 5) * 272 + 128 * h + 8 * Xs + qq + 5], s0);
        out[nb + (2 * b + ys) * 32 + 16 * h + Xs] = s0;
    }
}

extern "C" void kernel_launch(void* const* d_in, const int* in_sizes, int n_in,
                              void* d_out, int out_size, void* d_ws, size_t ws_size,
                              hipStream_t stream) {
    const float* img    = (const float*)d_in[0];
    const float* psi_re = (const float*)d_in[1];
    const float* psi_im = (const float*)d_in[2];
    const float* blur   = (const float*)d_in[3];
    float* out = (float*)d_out;
    float* ws = (float*)d_ws;
    float* pimg = ws + PIMG_OFF;
    float* s1p  = ws + S1P_OFF;
    float* fhp  = ws + FHP_OFF;

    dim3 g1(16, 16, 9);
    k_s1<<<g1, 640, 0, stream>>>(img, psi_re, psi_im, blur, pimg, s1p, fhp);

    dim3 g2(32, 11, 8);
    k_main5<<<g2, 320, 0, stream>>>(pimg, s1p, fhp, blur, out);
}